// Round 2
// baseline (958.769 us; speedup 1.0000x reference)
//
#include <hip/hip_runtime.h>
#include <math.h>

// VQ-VAE EMA vector quantizer, MI355X. Round 3 (resubmit): 8-phase counted-vmcnt
// 256x256 MFMA distance GEMM (T1+T2+T3+T4+T5), fp16-split as K=768 concatenated GEMM.
// N=32768 rows, D=256, K=8192 codes.

#define KC 8192
#define DD 256
#define NV 32768

typedef _Float16 f16;
typedef _Float16 f16x8 __attribute__((ext_vector_type(8)));
typedef _Float16 f16x4 __attribute__((ext_vector_type(4)));
typedef float f32x4 __attribute__((ext_vector_type(4)));

// ---------- x NCHW fp32 -> xh/xl f16 [n][d], plus sum(x^2) ----------
__global__ __launch_bounds__(256, 2) void k_convert_x(
    const float* __restrict__ x, f16* __restrict__ xh, f16* __restrict__ xl,
    float* __restrict__ lossAcc) {
    __shared__ float xs[256][68];
    __shared__ float red[4];
    const int t = threadIdx.x;
    const int n0 = blockIdx.x * 64;
    const int b = n0 >> 10;
    const int h0 = (n0 >> 5) & 31;
    {
        const int p = t >> 7, tt = t & 127;
        const int wq = (tt & 7) * 4, d0 = tt >> 3;
        const float* src = x + (size_t)b * 262144 + (size_t)(h0 + p) * 32 + wq;
        float s2 = 0.f;
        #pragma unroll
        for (int i = 0; i < 16; ++i) {
            int d = d0 + i * 16;
            float4 v = *(const float4*)(src + (size_t)d * 1024);
            *(float4*)&xs[d][p * 32 + wq] = v;
            s2 += v.x * v.x + v.y * v.y + v.z * v.z + v.w * v.w;
        }
        for (int off = 32; off > 0; off >>= 1) s2 += __shfl_xor(s2, off);
        if ((t & 63) == 0) red[t >> 6] = s2;
    }
    __syncthreads();
    if (t == 0) atomicAdd(&lossAcc[1], red[0] + red[1] + red[2] + red[3]);
    {
        const int rr = t & 3, c = t >> 2;
        #pragma unroll
        for (int i = 0; i < 16; ++i) {
            int r = rr + i * 4;
            f16x4 hv, lv;
            #pragma unroll
            for (int q = 0; q < 4; ++q) {
                float v = xs[c * 4 + q][r];
                f16 h = (f16)v;
                float rem = v - (float)h;
                hv[q] = h; lv[q] = (f16)rem;
            }
            *(f16x4*)(xh + (size_t)(n0 + r) * DD + c * 4) = hv;
            *(f16x4*)(xl + (size_t)(n0 + r) * DD + c * 4) = lv;
        }
    }
}

// ---------- embed fp32 [d][k] -> eh/el f16 [k][d] (transposed, split) ----------
__global__ void k_convert_e(const float* __restrict__ embed,
                            f16* __restrict__ eh, f16* __restrict__ el) {
    int kt = blockIdx.x & 255, dt = blockIdx.x >> 8;
    int k0 = kt * 32, d0 = dt * 32;
    __shared__ float tile[32][33];
    int t = threadIdx.x;
    int kk = t & 31, ii = t >> 5;
    for (int p = 0; p < 4; ++p) {
        int d = ii + p * 8;
        tile[d][kk] = embed[(size_t)(d0 + d) * KC + k0 + kk];
    }
    __syncthreads();
    int dv = t & 31, kk2 = t >> 5;
    for (int p = 0; p < 4; ++p) {
        int k = kk2 + p * 8;
        float v = tile[dv][k];
        f16 h = (f16)v;
        float rem = v - (float)h;
        eh[(size_t)(k0 + k) * DD + d0 + dv] = h;
        el[(size_t)(k0 + k) * DD + d0 + dv] = (f16)rem;
    }
}

// ---------- enorm[k] = sum_d embed[d,k]^2 (exact fp32) ----------
__global__ void k_enorm(const float* __restrict__ embed, float* __restrict__ enorm) {
    int k = blockIdx.x * 256 + threadIdx.x;
    float s = 0.f;
    for (int d = 0; d < DD; ++d) { float v = embed[(size_t)d * KC + k]; s += v * v; }
    enorm[k] = s;
}

// ---------- 8-phase 256x256 MFMA distance GEMM + per-slab argmin ----------
// C[32768][8192] = A'.B'^T with A' = [xh|xl|xh], B' = [eh|eh|el], K=768 (12 K-tiles of 64).
// 512 threads = 8 waves (2 row-groups x 4 col-groups); per-wave C = 128x64.
// LDS: As/Bs [2 buf][256 rows][64 f16]; linear gload_lds dest + inverse-swizzled
// global source + XOR-swizzled ds_read (chunk ^= row&7, 16B chunks).

__device__ __forceinline__ void gload16(const void* g, void* l) {
    __builtin_amdgcn_global_load_lds(
        (const __attribute__((address_space(1))) void*)g,
        (__attribute__((address_space(3))) void*)l, 16, 0, 0);
}

#define CFENCE asm volatile("" ::: "memory")
#define BAR()  do { CFENCE; __builtin_amdgcn_s_barrier(); CFENCE; } while (0)
#define WAITV(N) asm volatile("s_waitcnt vmcnt(" #N ")" ::: "memory")
#define WAITL0   asm volatile("s_waitcnt lgkmcnt(0)" ::: "memory")

// stage one A quarter (rows [wr*128 + QA*64, +64)) of K-tile KT into buffer BUF
#define STAGE_A(KT, QA, BUF) do { \
    const f16* _src = ((((KT) >> 2) & 3) == 1) ? xl : xh; \
    const int _cb = ((KT) & 3) * 64; \
    const int _rb = wr * 128 + (QA) * 64 + wsi * 16; \
    const f16* _g = _src + (size_t)(BR + _rb + (lane >> 3)) * DD + _cb + (((lane & 7) ^ (lane >> 3)) << 3); \
    char* _l = AsB + (BUF) * 32768 + _rb * 128; \
    gload16(_g, _l); \
    gload16(_g + 8 * DD, _l + 1024); \
} while (0)

// stage one B half (32 rows of each wc 64-block) of K-tile KT into buffer BUF
#define STAGE_B(KT, QC, BUF) do { \
    const f16* _src = ((((KT) >> 2) & 3) == 2) ? el : eh; \
    const int _cb = ((KT) & 3) * 64; \
    const int _rb = wc * 64 + (QC) * 32 + wr * 16; \
    const f16* _g = _src + (size_t)(CBb + _rb + (lane >> 3)) * DD + _cb + (((lane & 7) ^ (lane >> 3)) << 3); \
    char* _l = BsB + (BUF) * 32768 + _rb * 128; \
    gload16(_g, _l); \
    gload16(_g + 8 * DD, _l + 1024); \
} while (0)

#define RD_A(QA, BUF) do { \
    const char* _bse = AsB + (BUF) * 32768; \
    _Pragma("unroll") for (int i = 0; i < 4; ++i) { \
      const int _row = wr * 128 + (QA) * 64 + i * 16 + m; \
      _Pragma("unroll") for (int ks = 0; ks < 2; ++ks) \
        areg[i][ks] = *(const f16x8*)(_bse + _row * 128 + ((ks * 64 + q * 16) ^ swz)); \
    } \
} while (0)

#define RD_B(QC, BUF) do { \
    const char* _bse = BsB + (BUF) * 32768; \
    _Pragma("unroll") for (int j = 0; j < 2; ++j) { \
      const int _row = wc * 64 + (QC) * 32 + j * 16 + m; \
      _Pragma("unroll") for (int ks = 0; ks < 2; ++ks) \
        breg[j][ks] = *(const f16x8*)(_bse + _row * 128 + ((ks * 64 + q * 16) ^ swz)); \
    } \
} while (0)

#define MM(QR, QC) do { \
    _Pragma("unroll") for (int ks = 0; ks < 2; ++ks) \
    _Pragma("unroll") for (int j = 0; j < 2; ++j) \
    _Pragma("unroll") for (int i = 0; i < 4; ++i) \
        acc[QR][QC][i][j] = __builtin_amdgcn_mfma_f32_16x16x32_f16( \
            areg[i][ks], breg[j][ks], acc[QR][QC][i][j], 0, 0, 0); \
} while (0)

__global__ __launch_bounds__(512, 2) void k_argmin_mfma(
    const f16* __restrict__ xh, const f16* __restrict__ xl,
    const f16* __restrict__ eh, const f16* __restrict__ el,
    const float* __restrict__ enorm, unsigned long long* __restrict__ rowmin) {
    __shared__ f16 As[2][16384];   // 2 x [256 rows][64 f16]
    __shared__ f16 Bs[2][16384];
    __shared__ float en_s[256];
    // post-loop overlays (As buf0 is dead after kt=10; see barrier argument in notes):
    float* mval = (float*)&As[0][0];                 // [256][4]
    int*   midx = (int*)((char*)&As[0][0] + 4096);   // [256][4]

    const int t = threadIdx.x;
    const int lane = t & 63, wid = t >> 6;
    const int wr = wid >> 2, wc = wid & 3, wsi = wid & 3;
    const int m = lane & 15, q = lane >> 4;
    const int swz = (m & 7) << 4;

    // T1: bijective XCD swizzle (4096 % 8 == 0)
    const int wraw = blockIdx.x;
    const int wsw = ((wraw & 7) << 9) | (wraw >> 3);
    const int bx = wsw >> 5, by = wsw & 31;
    const int BR = bx * 256;   // row (x) base
    const int CBb = by * 256;  // col (code) base

    char* AsB = (char*)&As[0][0];
    char* BsB = (char*)&Bs[0][0];

    if (t < 256) en_s[t] = enorm[CBb + t];

    f32x4 acc[2][2][4][2];
    #pragma unroll
    for (int a0 = 0; a0 < 2; ++a0)
    #pragma unroll
    for (int a1 = 0; a1 < 2; ++a1)
    #pragma unroll
    for (int a2 = 0; a2 < 4; ++a2)
    #pragma unroll
    for (int a3 = 0; a3 < 2; ++a3) acc[a0][a1][a2][a3] = (f32x4){0.f, 0.f, 0.f, 0.f};

    f16x8 areg[4][2], breg[2][2];

    // prologue: stage K-tile 0, issue order Aq0, Bc0, Bc1, Aq1 (8 loads/wave)
    STAGE_A(0, 0, 0);
    STAGE_B(0, 0, 0);
    STAGE_B(0, 1, 0);
    STAGE_A(0, 1, 0);
    WAITV(4);       // Aq0, Bc0 landed (enorm load for waves 0-3 also retires here)
    BAR();

    for (int kt = 0; kt < 11; ++kt) {
        const int b = kt & 1, nb = b ^ 1;
        // phase 1: quadrant (0,0)
        RD_A(0, b); RD_B(0, b);
        STAGE_A(kt + 1, 0, nb);
        asm volatile("s_waitcnt lgkmcnt(8)" ::: "memory");
        BAR(); WAITL0;
        __builtin_amdgcn_s_setprio(1); MM(0, 0); __builtin_amdgcn_s_setprio(0);
        WAITV(4); BAR();           // confirms Bc1(kt) for phase 2
        // phase 2: quadrant (0,1)
        RD_B(1, b);
        STAGE_B(kt + 1, 0, nb);
        BAR(); WAITL0;
        __builtin_amdgcn_s_setprio(1); MM(0, 1); __builtin_amdgcn_s_setprio(0);
        WAITV(4); BAR();           // confirms Aq1(kt) for phase 3
        // phase 3: quadrant (1,1) (reuses breg = Bc1)
        RD_A(1, b);
        STAGE_B(kt + 1, 1, nb);
        BAR(); WAITL0;
        __builtin_amdgcn_s_setprio(1); MM(1, 1); __builtin_amdgcn_s_setprio(0);
        BAR();
        // phase 4: quadrant (1,0) (reuses areg = Aq1, reloads Bc0)
        RD_B(0, b);
        STAGE_A(kt + 1, 1, nb);
        BAR(); WAITL0;
        __builtin_amdgcn_s_setprio(1); MM(1, 0); __builtin_amdgcn_s_setprio(0);
        WAITV(4); BAR();           // confirms Aq0(kt+1), Bc0(kt+1) for next ph1
    }
    // epilogue K-tile 11 (buffer 1), no staging; drain 4 -> 2 -> 0
    {
        RD_A(0, 1); RD_B(0, 1);
        BAR(); WAITL0;
        __builtin_amdgcn_s_setprio(1); MM(0, 0); __builtin_amdgcn_s_setprio(0);
        WAITV(2); BAR();
        RD_B(1, 1);
        BAR(); WAITL0;
        __builtin_amdgcn_s_setprio(1); MM(0, 1); __builtin_amdgcn_s_setprio(0);
        WAITV(0); BAR();
        RD_A(1, 1);
        BAR(); WAITL0;
        __builtin_amdgcn_s_setprio(1); MM(1, 1); __builtin_amdgcn_s_setprio(0);
        BAR();
        RD_B(0, 1);
        WAITL0;
        __builtin_amdgcn_s_setprio(1); MM(1, 0); __builtin_amdgcn_s_setprio(0);
    }

    // ---- argmin epilogue: per-lane over (qc,j), shfl over 16 col-lanes, LDS merge ----
    #pragma unroll
    for (int qr = 0; qr < 2; ++qr)
    #pragma unroll
    for (int i = 0; i < 4; ++i)
    #pragma unroll
    for (int r = 0; r < 4; ++r) {
        float v = 3.4e38f; int ii = 0;
        #pragma unroll
        for (int qc = 0; qc < 2; ++qc)
        #pragma unroll
        for (int j = 0; j < 2; ++j) {
            int c = wc * 64 + qc * 32 + j * 16 + m;
            float dv = en_s[c] - 2.f * acc[qr][qc][i][j][r];
            if (dv < v) { v = dv; ii = CBb + c; }
        }
        #pragma unroll
        for (int off = 1; off < 16; off <<= 1) {
            float v2 = __shfl_xor(v, off);
            int i2 = __shfl_xor(ii, off);
            if (v2 < v || (v2 == v && i2 < ii)) { v = v2; ii = i2; }
        }
        if (m == 0) {
            int row = wr * 128 + qr * 64 + i * 16 + q * 4 + r;
            mval[row * 4 + wc] = v; midx[row * 4 + wc] = ii;
        }
    }
    __syncthreads();
    if (t < 256) {
        float v = mval[t * 4]; int ii = midx[t * 4];
        #pragma unroll
        for (int w2 = 1; w2 < 4; ++w2) {
            float v2 = mval[t * 4 + w2]; int i2 = midx[t * 4 + w2];
            if (v2 < v || (v2 == v && i2 < ii)) { v = v2; ii = i2; }
        }
        unsigned int u = __float_as_uint(v);
        u = (u & 0x80000000u) ? ~u : (u | 0x80000000u);
        unsigned long long key = ((unsigned long long)u << 32) | (unsigned int)ii;
        atomicMin(rowmin + BR + t, key);
    }
}

// ---------- decode rowmin -> idx, histogram, loss sum ----------
__global__ void k_finalize(const unsigned long long* __restrict__ rowmin,
                           int* __restrict__ idx, int* __restrict__ cnt,
                           float* __restrict__ lossAcc) {
    __shared__ float red[4];
    int t = threadIdx.x;
    int n = blockIdx.x * 256 + t;
    unsigned long long p = rowmin[n];
    unsigned int u = (unsigned int)(p >> 32);
    unsigned int u2 = (u & 0x80000000u) ? (u ^ 0x80000000u) : ~u;
    float v = __uint_as_float(u2);
    int i = (int)(unsigned int)(p & 0xFFFFFFFFu);
    idx[n] = i;
    atomicAdd(&cnt[i], 1);
    for (int off = 32; off > 0; off >>= 1) v += __shfl_xor(v, off);
    if ((t & 63) == 0) red[t >> 6] = v;
    __syncthreads();
    if (t == 0) atomicAdd(&lossAcc[0], red[0] + red[1] + red[2] + red[3]);
}

// ---------- single-block stats ----------
__global__ void k_stats(const int* __restrict__ cnt, const float* __restrict__ cluster_size,
                        const float* __restrict__ lossAcc,
                        float* __restrict__ out_ncs, float* __restrict__ out_loss,
                        float* __restrict__ out_perp,
                        float* __restrict__ smoothed, int* __restrict__ offsets) {
    __shared__ float rn[256], rp[256];
    __shared__ int rc[256];
    __shared__ int base_s[256];
    int t = threadIdx.x;
    float s_n = 0.f, s_pl = 0.f;
    int s_c = 0;
    float ncs_loc[32];
    #pragma unroll
    for (int i = 0; i < 32; ++i) {
        int k = t * 32 + i;
        int ci = cnt[k];
        float c = (float)ci;
        float ncs = cluster_size[k] * 0.99f + 0.01f * c;
        out_ncs[k] = ncs;
        ncs_loc[i] = ncs;
        s_n += ncs;
        float p = c * (1.0f / 32768.0f);
        s_pl += p * logf(p + 1e-10f);
        s_c += ci;
    }
    rn[t] = s_n; rp[t] = s_pl; rc[t] = s_c;
    for (int off = 128; off > 0; off >>= 1) {
        __syncthreads();
        if (t < off) { rn[t] += rn[t + off]; rp[t] += rp[t + off]; }
    }
    __syncthreads();
    float ntot = rn[0];
    if (t == 0) {
        out_loss[0] = 0.25f * (lossAcc[0] + lossAcc[1]) * (1.0f / 8388608.0f);
        out_perp[0] = expf(-rp[0]);
    }
    #pragma unroll
    for (int i = 0; i < 32; ++i) {
        int k = t * 32 + i;
        float ncs = ncs_loc[i];
        smoothed[k] = ntot * (ncs + 1e-5f) / (ntot + ncs * 1e-5f);
    }
    __syncthreads();
    if (t == 0) {
        int run = 0;
        for (int qq = 0; qq < 256; ++qq) { base_s[qq] = run; run += rc[qq]; }
    }
    __syncthreads();
    int run = base_s[t];
    #pragma unroll
    for (int i = 0; i < 32; ++i) {
        int k = t * 32 + i;
        offsets[k] = run;
        run += cnt[k];
    }
}

// ---------- counting-sort scatter ----------
__global__ void k_scatter(const int* __restrict__ idx, const int* __restrict__ offsets,
                          int* __restrict__ cursor, int* __restrict__ order) {
    int n = blockIdx.x * 256 + threadIdx.x;
    int k = idx[n];
    int pos = offsets[k] + atomicAdd(&cursor[k], 1);
    order[pos] = n;
}

// ---------- dwT[k][d] (f16) = segment_sum of x ----------
__global__ void k_dw(const int* __restrict__ cnt, const int* __restrict__ offsets,
                     const int* __restrict__ order, const f16* __restrict__ xh,
                     const f16* __restrict__ xl, f16* __restrict__ dwT) {
    int k = blockIdx.x;
    int t = threadIdx.x;
    int c = cnt[k], base = offsets[k];
    float s = 0.f;
    for (int i = 0; i < c; ++i) {
        int n = order[base + i];
        s += (float)xh[(size_t)n * DD + t] + (float)xl[(size_t)n * DD + t];
    }
    dwT[(size_t)k * DD + t] = (f16)s;
}

// ---------- new_ema_embed / new_embed ----------
__global__ void k_update_embed(const f16* __restrict__ dwT, const float* __restrict__ ema_embed,
                               const float* __restrict__ smoothed,
                               float* __restrict__ out_embed, float* __restrict__ out_ema) {
    __shared__ float tile[32][260];
    int bx = blockIdx.x, t = threadIdx.x;
    int d0 = (bx & 7) * 32, k0 = (bx >> 3) * 256;
    {
        int kk = t >> 3, dq = (t & 7) * 4;
        for (int i = 0; i < 8; ++i) {
            int kl = kk + i * 32;
            f16x4 v = *(const f16x4*)(dwT + (size_t)(k0 + kl) * DD + d0 + dq);
            tile[dq + 0][kl] = (float)v[0]; tile[dq + 1][kl] = (float)v[1];
            tile[dq + 2][kl] = (float)v[2]; tile[dq + 3][kl] = (float)v[3];
        }
    }
    __syncthreads();
    float sm = smoothed[k0 + t];
    for (int dv = 0; dv < 32; ++dv) {
        size_t o = (size_t)(d0 + dv) * KC + k0 + t;
        float dw = tile[dv][t];
        float ne = ema_embed[o] * 0.99f + 0.01f * dw;
        out_ema[o] = ne;
        out_embed[o] = ne / sm;
    }
}

// ---------- quantize gather + NCHW writeback ----------
__global__ __launch_bounds__(256, 2) void k_quantize_out(
    const int* __restrict__ idx, const f16* __restrict__ eh, const f16* __restrict__ el,
    float* __restrict__ out) {
    __shared__ float qv[256][68];
    __shared__ int li[64];
    int t = threadIdx.x;
    int n0 = blockIdx.x * 64;
    int b = n0 >> 10, h0 = (n0 >> 5) & 31;
    if (t < 64) li[t] = idx[n0 + t];
    __syncthreads();
    {
        int r = t >> 2, dq4 = (t & 3) * 4;
        const f16* srch = eh + (size_t)li[r] * DD;
        const f16* srcl = el + (size_t)li[r] * DD;
        for (int i = 0; i < 16; ++i) {
            int d = dq4 + i * 16;
            f16x4 hv = *(const f16x4*)(srch + d);
            f16x4 lv = *(const f16x4*)(srcl + d);
            qv[d + 0][r] = (float)hv[0] + (float)lv[0];
            qv[d + 1][r] = (float)hv[1] + (float)lv[1];
            qv[d + 2][r] = (float)hv[2] + (float)lv[2];
            qv[d + 3][r] = (float)hv[3] + (float)lv[3];
        }
    }
    __syncthreads();
    {
        int p = t >> 7, tt = t & 127;
        int wq = (tt & 7) * 4, d0 = tt >> 3;
        float* dst = out + (size_t)b * 262144 + (size_t)(h0 + p) * 32 + wq;
        for (int i = 0; i < 16; ++i) {
            int d = d0 + i * 16;
            float4 v = *(const float4*)&qv[d][p * 32 + wq];
            *(float4*)(dst + (size_t)d * 1024) = v;
        }
    }
}

extern "C" void kernel_launch(void* const* d_in, const int* in_sizes, int n_in,
                              void* d_out, int out_size, void* d_ws, size_t ws_size,
                              hipStream_t stream) {
    (void)in_sizes; (void)n_in; (void)out_size; (void)ws_size;
    const float* x            = (const float*)d_in[0];
    const float* embed        = (const float*)d_in[1];
    const float* cluster_size = (const float*)d_in[2];
    const float* ema_embed    = (const float*)d_in[3];
    float* out = (float*)d_out;
    char* ws = (char*)d_ws;

    f16*   xh       = (f16*)  (ws + 0);           // 16,777,216
    f16*   xl       = (f16*)  (ws + 16777216);    // 16,777,216
    f16*   eh       = (f16*)  (ws + 33554432);    //  4,194,304
    f16*   el       = (f16*)  (ws + 37748736);    //  4,194,304
    float* enorm    = (float*)(ws + 41943040);    //     32,768
    float* smoothed = (float*)(ws + 41975808);    //     32,768
    int*   idx      = (int*)  (ws + 42008576);    //    131,072
    int*   cnt      = (int*)  (ws + 42139648);    //     32,768
    int*   cursor   = (int*)  (ws + 42172416);    //     32,768
    int*   offsets  = (int*)  (ws + 42205184);    //     32,768
    float* lossAcc  = (float*)(ws + 42237952);    //        256 (padded)
    unsigned long long* rowmin = (unsigned long long*)(ws + 42238208); // 262,144
    int*   order    = (int*)  (ws + 42238208);    // aliases rowmin (used after finalize)
    f16*   dwT      = (f16*)  (ws + 42500352);    //  4,194,304  -> total 46,694,656

    float* out_q    = out;
    float* out_loss = out + 8388608;
    float* out_perp = out + 8388609;
    float* out_ncs  = out + 8388610;
    float* out_emb  = out + 8396802;
    float* out_ema  = out + 10493954;

    hipMemsetAsync(cnt, 0, 65536, stream);          // cnt + cursor adjacent
    hipMemsetAsync(lossAcc, 0, 8, stream);
    hipMemsetAsync(rowmin, 0xFF, 262144, stream);

    k_convert_x<<<512, 256, 0, stream>>>(x, xh, xl, lossAcc);
    k_convert_e<<<2048, 256, 0, stream>>>(embed, eh, el);
    k_enorm<<<32, 256, 0, stream>>>(embed, enorm);
    k_argmin_mfma<<<4096, 512, 0, stream>>>(xh, xl, eh, el, enorm, rowmin);
    k_finalize<<<128, 256, 0, stream>>>(rowmin, idx, cnt, lossAcc);
    k_stats<<<1, 256, 0, stream>>>(cnt, cluster_size, lossAcc, out_ncs, out_loss, out_perp,
                                   smoothed, offsets);
    k_scatter<<<128, 256, 0, stream>>>(idx, offsets, cursor, order);
    k_dw<<<8192, 256, 0, stream>>>(cnt, offsets, order, xh, xl, dwT);
    k_update_embed<<<256, 256, 0, stream>>>(dwT, ema_embed, smoothed, out_emb, out_ema);
    k_quantize_out<<<512, 256, 0, stream>>>(idx, eh, el, out_q);
}

// Round 3
// 945.481 us; speedup vs baseline: 1.0141x; 1.0141x over previous
//
#include <hip/hip_runtime.h>
#include <math.h>

// VQ-VAE EMA vector quantizer, MI355X. Round 4: 256x256 MFMA distance GEMM,
// single-barrier-per-K-tile, early-stage + drain, swizzled gload_lds staging,
// L2-friendly XCD-chunked dispatch. fp16-split as K=768 concatenated GEMM.
// N=32768 rows, D=256, K=8192 codes.

#define KC 8192
#define DD 256
#define NV 32768

typedef _Float16 f16;
typedef _Float16 f16x8 __attribute__((ext_vector_type(8)));
typedef _Float16 f16x4 __attribute__((ext_vector_type(4)));
typedef float f32x4 __attribute__((ext_vector_type(4)));

// ---------- x NCHW fp32 -> xh/xl f16 [n][d], plus sum(x^2) ----------
__global__ __launch_bounds__(256, 2) void k_convert_x(
    const float* __restrict__ x, f16* __restrict__ xh, f16* __restrict__ xl,
    float* __restrict__ lossAcc) {
    __shared__ float xs[256][68];
    __shared__ float red[4];
    const int t = threadIdx.x;
    const int n0 = blockIdx.x * 64;
    const int b = n0 >> 10;
    const int h0 = (n0 >> 5) & 31;
    {
        const int p = t >> 7, tt = t & 127;
        const int wq = (tt & 7) * 4, d0 = tt >> 3;
        const float* src = x + (size_t)b * 262144 + (size_t)(h0 + p) * 32 + wq;
        float s2 = 0.f;
        #pragma unroll
        for (int i = 0; i < 16; ++i) {
            int d = d0 + i * 16;
            float4 v = *(const float4*)(src + (size_t)d * 1024);
            *(float4*)&xs[d][p * 32 + wq] = v;
            s2 += v.x * v.x + v.y * v.y + v.z * v.z + v.w * v.w;
        }
        for (int off = 32; off > 0; off >>= 1) s2 += __shfl_xor(s2, off);
        if ((t & 63) == 0) red[t >> 6] = s2;
    }
    __syncthreads();
    if (t == 0) atomicAdd(&lossAcc[1], red[0] + red[1] + red[2] + red[3]);
    {
        const int rr = t & 3, c = t >> 2;
        #pragma unroll
        for (int i = 0; i < 16; ++i) {
            int r = rr + i * 4;
            f16x4 hv, lv;
            #pragma unroll
            for (int q = 0; q < 4; ++q) {
                float v = xs[c * 4 + q][r];
                f16 h = (f16)v;
                float rem = v - (float)h;
                hv[q] = h; lv[q] = (f16)rem;
            }
            *(f16x4*)(xh + (size_t)(n0 + r) * DD + c * 4) = hv;
            *(f16x4*)(xl + (size_t)(n0 + r) * DD + c * 4) = lv;
        }
    }
}

// ---------- embed fp32 [d][k] -> eh/el f16 [k][d] (transposed, split) ----------
__global__ void k_convert_e(const float* __restrict__ embed,
                            f16* __restrict__ eh, f16* __restrict__ el) {
    int kt = blockIdx.x & 255, dt = blockIdx.x >> 8;
    int k0 = kt * 32, d0 = dt * 32;
    __shared__ float tile[32][33];
    int t = threadIdx.x;
    int kk = t & 31, ii = t >> 5;
    for (int p = 0; p < 4; ++p) {
        int d = ii + p * 8;
        tile[d][kk] = embed[(size_t)(d0 + d) * KC + k0 + kk];
    }
    __syncthreads();
    int dv = t & 31, kk2 = t >> 5;
    for (int p = 0; p < 4; ++p) {
        int k = kk2 + p * 8;
        float v = tile[dv][k];
        f16 h = (f16)v;
        float rem = v - (float)h;
        eh[(size_t)(k0 + k) * DD + d0 + dv] = h;
        el[(size_t)(k0 + k) * DD + d0 + dv] = (f16)rem;
    }
}

// ---------- enorm[k] = sum_d embed[d,k]^2 (exact fp32) ----------
__global__ void k_enorm(const float* __restrict__ embed, float* __restrict__ enorm) {
    int k = blockIdx.x * 256 + threadIdx.x;
    float s = 0.f;
    for (int d = 0; d < DD; ++d) { float v = embed[(size_t)d * KC + k]; s += v * v; }
    enorm[k] = s;
}

// ---------- MFMA distance GEMM + per-slab argmin ----------
// C[32768][8192] = A'.B'^T, A' = [xh|xl|xh], B' = [eh|eh|el], K=768 (12 K-tiles of 64).
// 512 threads = 8 waves (2 row x 4 col groups); per-wave C = 128x64.
// Per K-tile: stage ALL of tile kt+1 (8 gload_lds) at top, 24 ds_read_b128,
// 64 MFMA in two 32-clusters, one vmcnt(0) drain + one barrier at bottom.
// LDS linear-dest gload + inverse-swizzled global src + XOR-swizzled ds_read.

__device__ __forceinline__ void gload16(const void* g, void* l) {
    __builtin_amdgcn_global_load_lds(
        (const __attribute__((address_space(1))) void*)g,
        (__attribute__((address_space(3))) void*)l, 16, 0, 0);
}

#define CFENCE asm volatile("" ::: "memory")
#define BAR()  do { CFENCE; __builtin_amdgcn_s_barrier(); CFENCE; } while (0)
#define WAITV0 asm volatile("s_waitcnt vmcnt(0)" ::: "memory")

// stage full A half-tile rows for this wave: rows base+{0..15}, base+{64..79}
#define STAGE_A(KT, BUF) do { \
    const f16* _s = (((KT) >> 2) == 1) ? xl : xh; \
    const f16* _g = _s + aoff + (size_t)(((KT) & 3) * 64); \
    char* _l = ldsA0 + (BUF) * 32768; \
    gload16(_g, _l);            gload16(_g + 8 * DD, _l + 1024); \
    gload16(_g + 64 * DD, _l + 8192); gload16(_g + 72 * DD, _l + 9216); \
} while (0)

// stage full B rows for this wave: rows base+{0..15}, base+{32..47}
#define STAGE_B(KT, BUF) do { \
    const f16* _s = (((KT) >> 2) == 2) ? el : eh; \
    const f16* _g = _s + boff + (size_t)(((KT) & 3) * 64); \
    char* _l = ldsB0 + (BUF) * 32768; \
    gload16(_g, _l);            gload16(_g + 8 * DD, _l + 1024); \
    gload16(_g + 32 * DD, _l + 4096); gload16(_g + 40 * DD, _l + 5120); \
} while (0)

#define RD_A(QA, BUF) do { \
    const char* _bse = AsB + (BUF) * 32768; \
    _Pragma("unroll") for (int i = 0; i < 4; ++i) { \
      const int _row = wr * 128 + (QA) * 64 + i * 16 + m; \
      _Pragma("unroll") for (int ks = 0; ks < 2; ++ks) \
        areg[i][ks] = *(const f16x8*)(_bse + _row * 128 + ((ks * 64 + q * 16) ^ swz)); \
    } \
} while (0)

#define RD_B(QC, BUF) do { \
    const char* _bse = BsB + (BUF) * 32768; \
    _Pragma("unroll") for (int j = 0; j < 2; ++j) { \
      const int _row = wc * 64 + (QC) * 32 + j * 16 + m; \
      _Pragma("unroll") for (int ks = 0; ks < 2; ++ks) \
        breg[(QC) * 2 + j][ks] = *(const f16x8*)(_bse + _row * 128 + ((ks * 64 + q * 16) ^ swz)); \
    } \
} while (0)

#define MM(QR, QC) do { \
    _Pragma("unroll") for (int ks = 0; ks < 2; ++ks) \
    _Pragma("unroll") for (int j = 0; j < 2; ++j) \
    _Pragma("unroll") for (int i = 0; i < 4; ++i) \
        acc[QR][QC][i][j] = __builtin_amdgcn_mfma_f32_16x16x32_f16( \
            areg[i][ks], breg[(QC) * 2 + j][ks], acc[QR][QC][i][j], 0, 0, 0); \
} while (0)

__global__ __launch_bounds__(512, 2) void k_argmin_mfma(
    const f16* __restrict__ xh, const f16* __restrict__ xl,
    const f16* __restrict__ eh, const f16* __restrict__ el,
    const float* __restrict__ enorm, unsigned long long* __restrict__ rowmin) {
    __shared__ f16 As[2][16384];   // 2 x [256 rows][64 f16]
    __shared__ f16 Bs[2][16384];
    __shared__ float en_s[256];
    // post-loop overlays (As buf0 dead after kt=10; final tile reads buf1):
    float* mval = (float*)&As[0][0];                 // [256][4]
    int*   midx = (int*)((char*)&As[0][0] + 4096);   // [256][4]

    const int t = threadIdx.x;
    const int lane = t & 63, wid = t >> 6;
    const int wr = wid >> 2, wc = wid & 3, wsi = wid & 3;
    const int m = lane & 15, q = lane >> 4;
    const int swz = (m & 7) << 4;

    // dispatch map: each XCD owns 16 contiguous row-blocks; col-panel outermost.
    // B-panel (393KB) stays L2-resident per XCD; x-chunk (6.3MB/XCD) LLC-resident.
    const int bid = blockIdx.x;
    const int xcd = bid & 7, seq = bid >> 3;
    const int colb = seq >> 4;                 // 0..31
    const int rowb = (xcd << 4) | (seq & 15);  // 0..127
    const int BR = rowb * 256;
    const int CBb = colb * 256;

    char* AsB = (char*)&As[0][0];
    char* BsB = (char*)&Bs[0][0];

    if (t < 256) en_s[t] = enorm[CBb + t];

    // hoisted per-lane staging offsets (elements); per-stage adds are tiny
    const int l8 = lane >> 3, l7 = lane & 7;
    const size_t aoff = (size_t)(BR + wr * 128 + wsi * 16 + l8) * DD + (size_t)((l7 ^ l8) << 3);
    const size_t boff = (size_t)(CBb + wc * 64 + wr * 16 + l8) * DD + (size_t)((l7 ^ l8) << 3);
    char* const ldsA0 = AsB + (wr * 128 + wsi * 16) * 128;
    char* const ldsB0 = BsB + (wc * 64 + wr * 16) * 128;

    f32x4 acc[2][2][4][2];
    #pragma unroll
    for (int a0 = 0; a0 < 2; ++a0)
    #pragma unroll
    for (int a1 = 0; a1 < 2; ++a1)
    #pragma unroll
    for (int a2 = 0; a2 < 4; ++a2)
    #pragma unroll
    for (int a3 = 0; a3 < 2; ++a3) acc[a0][a1][a2][a3] = (f32x4){0.f, 0.f, 0.f, 0.f};

    f16x8 areg[4][2], breg[4][2];

    // prologue: stage K-tile 0, drain, barrier
    STAGE_A(0, 0);
    STAGE_B(0, 0);
    WAITV0;
    BAR();

    #pragma unroll 1
    for (int kt = 0; kt < 11; ++kt) {
        const int b = kt & 1, nb = b ^ 1;
        // issue next tile's 8 staging loads FIRST -> full tile body of latency slack
        STAGE_A(kt + 1, nb);
        STAGE_B(kt + 1, nb);
        // compute current tile
        RD_A(0, b); RD_B(0, b); RD_B(1, b);
        __builtin_amdgcn_s_setprio(1); MM(0, 0); MM(0, 1); __builtin_amdgcn_s_setprio(0);
        RD_A(1, b);
        __builtin_amdgcn_s_setprio(1); MM(1, 0); MM(1, 1); __builtin_amdgcn_s_setprio(0);
        WAITV0;   // staging loads issued a full tile ago -> near-free
        BAR();
    }
    // final K-tile 11 (buffer 1), nothing outstanding
    RD_A(0, 1); RD_B(0, 1); RD_B(1, 1);
    __builtin_amdgcn_s_setprio(1); MM(0, 0); MM(0, 1); __builtin_amdgcn_s_setprio(0);
    RD_A(1, 1);
    __builtin_amdgcn_s_setprio(1); MM(1, 0); MM(1, 1); __builtin_amdgcn_s_setprio(0);

    // ---- argmin epilogue: per-lane over (qc,j), shfl over 16 col-lanes, LDS merge ----
    #pragma unroll
    for (int qr = 0; qr < 2; ++qr)
    #pragma unroll
    for (int i = 0; i < 4; ++i)
    #pragma unroll
    for (int r = 0; r < 4; ++r) {
        float v = 3.4e38f; int ii = 0;
        #pragma unroll
        for (int qc = 0; qc < 2; ++qc)
        #pragma unroll
        for (int j = 0; j < 2; ++j) {
            int c = wc * 64 + qc * 32 + j * 16 + m;
            float dv = en_s[c] - 2.f * acc[qr][qc][i][j][r];
            if (dv < v) { v = dv; ii = CBb + c; }
        }
        #pragma unroll
        for (int off = 1; off < 16; off <<= 1) {
            float v2 = __shfl_xor(v, off);
            int i2 = __shfl_xor(ii, off);
            if (v2 < v || (v2 == v && i2 < ii)) { v = v2; ii = i2; }
        }
        if (m == 0) {
            int row = wr * 128 + qr * 64 + i * 16 + q * 4 + r;
            mval[row * 4 + wc] = v; midx[row * 4 + wc] = ii;
        }
    }
    __syncthreads();
    if (t < 256) {
        float v = mval[t * 4]; int ii = midx[t * 4];
        #pragma unroll
        for (int w2 = 1; w2 < 4; ++w2) {
            float v2 = mval[t * 4 + w2]; int i2 = midx[t * 4 + w2];
            if (v2 < v || (v2 == v && i2 < ii)) { v = v2; ii = i2; }
        }
        unsigned int u = __float_as_uint(v);
        u = (u & 0x80000000u) ? ~u : (u | 0x80000000u);
        unsigned long long key = ((unsigned long long)u << 32) | (unsigned int)ii;
        atomicMin(rowmin + BR + t, key);
    }
}

// ---------- decode rowmin -> idx, histogram, loss sum ----------
__global__ void k_finalize(const unsigned long long* __restrict__ rowmin,
                           int* __restrict__ idx, int* __restrict__ cnt,
                           float* __restrict__ lossAcc) {
    __shared__ float red[4];
    int t = threadIdx.x;
    int n = blockIdx.x * 256 + t;
    unsigned long long p = rowmin[n];
    unsigned int u = (unsigned int)(p >> 32);
    unsigned int u2 = (u & 0x80000000u) ? (u ^ 0x80000000u) : ~u;
    float v = __uint_as_float(u2);
    int i = (int)(unsigned int)(p & 0xFFFFFFFFu);
    idx[n] = i;
    atomicAdd(&cnt[i], 1);
    for (int off = 32; off > 0; off >>= 1) v += __shfl_xor(v, off);
    if ((t & 63) == 0) red[t >> 6] = v;
    __syncthreads();
    if (t == 0) atomicAdd(&lossAcc[0], red[0] + red[1] + red[2] + red[3]);
}

// ---------- single-block stats ----------
__global__ void k_stats(const int* __restrict__ cnt, const float* __restrict__ cluster_size,
                        const float* __restrict__ lossAcc,
                        float* __restrict__ out_ncs, float* __restrict__ out_loss,
                        float* __restrict__ out_perp,
                        float* __restrict__ smoothed, int* __restrict__ offsets) {
    __shared__ float rn[256], rp[256];
    __shared__ int rc[256];
    __shared__ int base_s[256];
    int t = threadIdx.x;
    float s_n = 0.f, s_pl = 0.f;
    int s_c = 0;
    float ncs_loc[32];
    #pragma unroll
    for (int i = 0; i < 32; ++i) {
        int k = t * 32 + i;
        int ci = cnt[k];
        float c = (float)ci;
        float ncs = cluster_size[k] * 0.99f + 0.01f * c;
        out_ncs[k] = ncs;
        ncs_loc[i] = ncs;
        s_n += ncs;
        float p = c * (1.0f / 32768.0f);
        s_pl += p * logf(p + 1e-10f);
        s_c += ci;
    }
    rn[t] = s_n; rp[t] = s_pl; rc[t] = s_c;
    for (int off = 128; off > 0; off >>= 1) {
        __syncthreads();
        if (t < off) { rn[t] += rn[t + off]; rp[t] += rp[t + off]; }
    }
    __syncthreads();
    float ntot = rn[0];
    if (t == 0) {
        out_loss[0] = 0.25f * (lossAcc[0] + lossAcc[1]) * (1.0f / 8388608.0f);
        out_perp[0] = expf(-rp[0]);
    }
    #pragma unroll
    for (int i = 0; i < 32; ++i) {
        int k = t * 32 + i;
        float ncs = ncs_loc[i];
        smoothed[k] = ntot * (ncs + 1e-5f) / (ntot + ncs * 1e-5f);
    }
    __syncthreads();
    if (t == 0) {
        int run = 0;
        for (int qq = 0; qq < 256; ++qq) { base_s[qq] = run; run += rc[qq]; }
    }
    __syncthreads();
    int run = base_s[t];
    #pragma unroll
    for (int i = 0; i < 32; ++i) {
        int k = t * 32 + i;
        offsets[k] = run;
        run += cnt[k];
    }
}

// ---------- counting-sort scatter ----------
__global__ void k_scatter(const int* __restrict__ idx, const int* __restrict__ offsets,
                          int* __restrict__ cursor, int* __restrict__ order) {
    int n = blockIdx.x * 256 + threadIdx.x;
    int k = idx[n];
    int pos = offsets[k] + atomicAdd(&cursor[k], 1);
    order[pos] = n;
}

// ---------- dwT[k][d] (f16) = segment_sum of x ----------
__global__ void k_dw(const int* __restrict__ cnt, const int* __restrict__ offsets,
                     const int* __restrict__ order, const f16* __restrict__ xh,
                     const f16* __restrict__ xl, f16* __restrict__ dwT) {
    int k = blockIdx.x;
    int t = threadIdx.x;
    int c = cnt[k], base = offsets[k];
    float s = 0.f;
    for (int i = 0; i < c; ++i) {
        int n = order[base + i];
        s += (float)xh[(size_t)n * DD + t] + (float)xl[(size_t)n * DD + t];
    }
    dwT[(size_t)k * DD + t] = (f16)s;
}

// ---------- new_ema_embed / new_embed ----------
__global__ void k_update_embed(const f16* __restrict__ dwT, const float* __restrict__ ema_embed,
                               const float* __restrict__ smoothed,
                               float* __restrict__ out_embed, float* __restrict__ out_ema) {
    __shared__ float tile[32][260];
    int bx = blockIdx.x, t = threadIdx.x;
    int d0 = (bx & 7) * 32, k0 = (bx >> 3) * 256;
    {
        int kk = t >> 3, dq = (t & 7) * 4;
        for (int i = 0; i < 8; ++i) {
            int kl = kk + i * 32;
            f16x4 v = *(const f16x4*)(dwT + (size_t)(k0 + kl) * DD + d0 + dq);
            tile[dq + 0][kl] = (float)v[0]; tile[dq + 1][kl] = (float)v[1];
            tile[dq + 2][kl] = (float)v[2]; tile[dq + 3][kl] = (float)v[3];
        }
    }
    __syncthreads();
    float sm = smoothed[k0 + t];
    for (int dv = 0; dv < 32; ++dv) {
        size_t o = (size_t)(d0 + dv) * KC + k0 + t;
        float dw = tile[dv][t];
        float ne = ema_embed[o] * 0.99f + 0.01f * dw;
        out_ema[o] = ne;
        out_embed[o] = ne / sm;
    }
}

// ---------- quantize gather + NCHW writeback ----------
__global__ __launch_bounds__(256, 2) void k_quantize_out(
    const int* __restrict__ idx, const f16* __restrict__ eh, const f16* __restrict__ el,
    float* __restrict__ out) {
    __shared__ float qv[256][68];
    __shared__ int li[64];
    int t = threadIdx.x;
    int n0 = blockIdx.x * 64;
    int b = n0 >> 10, h0 = (n0 >> 5) & 31;
    if (t < 64) li[t] = idx[n0 + t];
    __syncthreads();
    {
        int r = t >> 2, dq4 = (t & 3) * 4;
        const f16* srch = eh + (size_t)li[r] * DD;
        const f16* srcl = el + (size_t)li[r] * DD;
        for (int i = 0; i < 16; ++i) {
            int d = dq4 + i * 16;
            f16x4 hv = *(const f16x4*)(srch + d);
            f16x4 lv = *(const f16x4*)(srcl + d);
            qv[d + 0][r] = (float)hv[0] + (float)lv[0];
            qv[d + 1][r] = (float)hv[1] + (float)lv[1];
            qv[d + 2][r] = (float)hv[2] + (float)lv[2];
            qv[d + 3][r] = (float)hv[3] + (float)lv[3];
        }
    }
    __syncthreads();
    {
        int p = t >> 7, tt = t & 127;
        int wq = (tt & 7) * 4, d0 = tt >> 3;
        float* dst = out + (size_t)b * 262144 + (size_t)(h0 + p) * 32 + wq;
        for (int i = 0; i < 16; ++i) {
            int d = d0 + i * 16;
            float4 v = *(const float4*)&qv[d][p * 32 + wq];
            *(float4*)(dst + (size_t)d * 1024) = v;
        }
    }
}

extern "C" void kernel_launch(void* const* d_in, const int* in_sizes, int n_in,
                              void* d_out, int out_size, void* d_ws, size_t ws_size,
                              hipStream_t stream) {
    (void)in_sizes; (void)n_in; (void)out_size; (void)ws_size;
    const float* x            = (const float*)d_in[0];
    const float* embed        = (const float*)d_in[1];
    const float* cluster_size = (const float*)d_in[2];
    const float* ema_embed    = (const float*)d_in[3];
    float* out = (float*)d_out;
    char* ws = (char*)d_ws;

    f16*   xh       = (f16*)  (ws + 0);           // 16,777,216
    f16*   xl       = (f16*)  (ws + 16777216);    // 16,777,216
    f16*   eh       = (f16*)  (ws + 33554432);    //  4,194,304
    f16*   el       = (f16*)  (ws + 37748736);    //  4,194,304
    float* enorm    = (float*)(ws + 41943040);    //     32,768
    float* smoothed = (float*)(ws + 41975808);    //     32,768
    int*   idx      = (int*)  (ws + 42008576);    //    131,072
    int*   cnt      = (int*)  (ws + 42139648);    //     32,768
    int*   cursor   = (int*)  (ws + 42172416);    //     32,768
    int*   offsets  = (int*)  (ws + 42205184);    //     32,768
    float* lossAcc  = (float*)(ws + 42237952);    //        256 (padded)
    unsigned long long* rowmin = (unsigned long long*)(ws + 42238208); // 262,144
    int*   order    = (int*)  (ws + 42238208);    // aliases rowmin (used after finalize)
    f16*   dwT      = (f16*)  (ws + 42500352);    //  4,194,304  -> total 46,694,656

    float* out_q    = out;
    float* out_loss = out + 8388608;
    float* out_perp = out + 8388609;
    float* out_ncs  = out + 8388610;
    float* out_emb  = out + 8396802;
    float* out_ema  = out + 10493954;

    hipMemsetAsync(cnt, 0, 65536, stream);          // cnt + cursor adjacent
    hipMemsetAsync(lossAcc, 0, 8, stream);
    hipMemsetAsync(rowmin, 0xFF, 262144, stream);

    k_convert_x<<<512, 256, 0, stream>>>(x, xh, xl, lossAcc);
    k_convert_e<<<2048, 256, 0, stream>>>(embed, eh, el);
    k_enorm<<<32, 256, 0, stream>>>(embed, enorm);
    k_argmin_mfma<<<4096, 512, 0, stream>>>(xh, xl, eh, el, enorm, rowmin);
    k_finalize<<<128, 256, 0, stream>>>(rowmin, idx, cnt, lossAcc);
    k_stats<<<1, 256, 0, stream>>>(cnt, cluster_size, lossAcc, out_ncs, out_loss, out_perp,
                                   smoothed, offsets);
    k_scatter<<<128, 256, 0, stream>>>(idx, offsets, cursor, order);
    k_dw<<<8192, 256, 0, stream>>>(cnt, offsets, order, xh, xl, dwT);
    k_update_embed<<<256, 256, 0, stream>>>(dwT, ema_embed, smoothed, out_emb, out_ema);
    k_quantize_out<<<512, 256, 0, stream>>>(idx, eh, el, out_q);
}

// Round 4
// 879.249 us; speedup vs baseline: 1.0904x; 1.0753x over previous
//
#include <hip/hip_runtime.h>
#include <math.h>

// VQ-VAE EMA vector quantizer, MI355X. Round 5: occupancy-first MFMA GEMM.
// 256x128 tile, 8 waves (4x2), 64x64/wave, BK=32, double-buffered 48.5KB LDS,
// launch_bounds(512,4) -> 2 blocks/CU = 16 waves/CU (2x round-4 TLP).
// Superrow-swizzled LDS (conflict-free), gload_lds staging, XCD-chunked grid.
// fp16-split distance GEMM as K=768 concatenated GEMM. N=32768, D=256, K=8192.

#define KC 8192
#define DD 256
#define NV 32768

typedef _Float16 f16;
typedef _Float16 f16x8 __attribute__((ext_vector_type(8)));
typedef _Float16 f16x4 __attribute__((ext_vector_type(4)));
typedef float f32x4 __attribute__((ext_vector_type(4)));

// ---------- x NCHW fp32 -> xh/xl f16 [n][d], plus sum(x^2) ----------
__global__ __launch_bounds__(256, 2) void k_convert_x(
    const float* __restrict__ x, f16* __restrict__ xh, f16* __restrict__ xl,
    float* __restrict__ lossAcc) {
    __shared__ float xs[256][68];
    __shared__ float red[4];
    const int t = threadIdx.x;
    const int n0 = blockIdx.x * 64;
    const int b = n0 >> 10;
    const int h0 = (n0 >> 5) & 31;
    {
        const int p = t >> 7, tt = t & 127;
        const int wq = (tt & 7) * 4, d0 = tt >> 3;
        const float* src = x + (size_t)b * 262144 + (size_t)(h0 + p) * 32 + wq;
        float s2 = 0.f;
        #pragma unroll
        for (int i = 0; i < 16; ++i) {
            int d = d0 + i * 16;
            float4 v = *(const float4*)(src + (size_t)d * 1024);
            *(float4*)&xs[d][p * 32 + wq] = v;
            s2 += v.x * v.x + v.y * v.y + v.z * v.z + v.w * v.w;
        }
        for (int off = 32; off > 0; off >>= 1) s2 += __shfl_xor(s2, off);
        if ((t & 63) == 0) red[t >> 6] = s2;
    }
    __syncthreads();
    if (t == 0) atomicAdd(&lossAcc[1], red[0] + red[1] + red[2] + red[3]);
    {
        const int rr = t & 3, c = t >> 2;
        #pragma unroll
        for (int i = 0; i < 16; ++i) {
            int r = rr + i * 4;
            f16x4 hv, lv;
            #pragma unroll
            for (int q = 0; q < 4; ++q) {
                float v = xs[c * 4 + q][r];
                f16 h = (f16)v;
                float rem = v - (float)h;
                hv[q] = h; lv[q] = (f16)rem;
            }
            *(f16x4*)(xh + (size_t)(n0 + r) * DD + c * 4) = hv;
            *(f16x4*)(xl + (size_t)(n0 + r) * DD + c * 4) = lv;
        }
    }
}

// ---------- embed fp32 [d][k] -> eh/el f16 [k][d] (transposed, split) ----------
__global__ void k_convert_e(const float* __restrict__ embed,
                            f16* __restrict__ eh, f16* __restrict__ el) {
    int kt = blockIdx.x & 255, dt = blockIdx.x >> 8;
    int k0 = kt * 32, d0 = dt * 32;
    __shared__ float tile[32][33];
    int t = threadIdx.x;
    int kk = t & 31, ii = t >> 5;
    for (int p = 0; p < 4; ++p) {
        int d = ii + p * 8;
        tile[d][kk] = embed[(size_t)(d0 + d) * KC + k0 + kk];
    }
    __syncthreads();
    int dv = t & 31, kk2 = t >> 5;
    for (int p = 0; p < 4; ++p) {
        int k = kk2 + p * 8;
        float v = tile[dv][k];
        f16 h = (f16)v;
        float rem = v - (float)h;
        eh[(size_t)(k0 + k) * DD + d0 + dv] = h;
        el[(size_t)(k0 + k) * DD + d0 + dv] = (f16)rem;
    }
}

// ---------- enorm[k] = sum_d embed[d,k]^2 (exact fp32) ----------
__global__ void k_enorm(const float* __restrict__ embed, float* __restrict__ enorm) {
    int k = blockIdx.x * 256 + threadIdx.x;
    float s = 0.f;
    for (int d = 0; d < DD; ++d) { float v = embed[(size_t)d * KC + k]; s += v * v; }
    enorm[k] = s;
}

// ---------- MFMA distance GEMM + per-slab argmin ----------
// C[32768][8192] = A'.B'^T, A' = [xh|xl|xh], B' = [eh|eh|el], K=768 = 24 tiles of 32.
// Block 256x128, 8 waves as 4x2, per-wave 64x64 (acc = 16 f32x4 = 64 VGPR).
// LDS superrow layout: 2 rows per 128B; 16B chunk c at (row r) stored at
// chunk c ^ ((r>>1)&7) within the superrow -> gload_lds write linear,
// ds_read_b128 balanced 8 lanes/bank-slot (conflict-free minimum).

__device__ __forceinline__ void gload16(const void* g, void* l) {
    __builtin_amdgcn_global_load_lds(
        (const __attribute__((address_space(1))) void*)g,
        (__attribute__((address_space(3))) void*)l, 16, 0, 0);
}

// stage K-tile KT into buffer NB: per wave 2 A-gloads (32 rows) + 1 B-gload (16 rows)
#define STAGE(KT, NB) do { \
    const f16* _sa = (((KT) >> 3) == 1) ? xl : xh; \
    const f16* _sb = (((KT) >> 3) == 2) ? el : eh; \
    const int _kc = ((KT) & 7) * 32; \
    const f16* _ga = _sa + aoff + _kc; \
    gload16(_ga, ldsAw + (NB) * 16384); \
    gload16(_ga + 16 * DD, ldsAw + (NB) * 16384 + 1024); \
    gload16(_sb + boff + _kc, ldsBw + (NB) * 8192); \
} while (0)

// compute tile KT from buffer B, staging KT+1 into NB; one barrier per tile
#define BODY(KT, B, NB) do { \
    STAGE((KT) + 1, NB); \
    const char* _ab = AsB + (B) * 16384 + abyte; \
    const char* _bb = BsB + (B) * 8192 + bbyte; \
    f16x8 _b0 = *(const f16x8*)(_bb); \
    f16x8 _b1 = *(const f16x8*)(_bb + 1024); \
    f16x8 _b2 = *(const f16x8*)(_bb + 2048); \
    f16x8 _b3 = *(const f16x8*)(_bb + 3072); \
    _Pragma("unroll") for (int _i = 0; _i < 4; ++_i) { \
        f16x8 _a = *(const f16x8*)(_ab + _i * 1024); \
        __builtin_amdgcn_s_setprio(1); \
        acc[_i][0] = __builtin_amdgcn_mfma_f32_16x16x32_f16(_a, _b0, acc[_i][0], 0, 0, 0); \
        acc[_i][1] = __builtin_amdgcn_mfma_f32_16x16x32_f16(_a, _b1, acc[_i][1], 0, 0, 0); \
        acc[_i][2] = __builtin_amdgcn_mfma_f32_16x16x32_f16(_a, _b2, acc[_i][2], 0, 0, 0); \
        acc[_i][3] = __builtin_amdgcn_mfma_f32_16x16x32_f16(_a, _b3, acc[_i][3], 0, 0, 0); \
        __builtin_amdgcn_s_setprio(0); \
    } \
    __syncthreads(); \
} while (0)

#define FINALT(B) do { \
    const char* _ab = AsB + (B) * 16384 + abyte; \
    const char* _bb = BsB + (B) * 8192 + bbyte; \
    f16x8 _b0 = *(const f16x8*)(_bb); \
    f16x8 _b1 = *(const f16x8*)(_bb + 1024); \
    f16x8 _b2 = *(const f16x8*)(_bb + 2048); \
    f16x8 _b3 = *(const f16x8*)(_bb + 3072); \
    _Pragma("unroll") for (int _i = 0; _i < 4; ++_i) { \
        f16x8 _a = *(const f16x8*)(_ab + _i * 1024); \
        __builtin_amdgcn_s_setprio(1); \
        acc[_i][0] = __builtin_amdgcn_mfma_f32_16x16x32_f16(_a, _b0, acc[_i][0], 0, 0, 0); \
        acc[_i][1] = __builtin_amdgcn_mfma_f32_16x16x32_f16(_a, _b1, acc[_i][1], 0, 0, 0); \
        acc[_i][2] = __builtin_amdgcn_mfma_f32_16x16x32_f16(_a, _b2, acc[_i][2], 0, 0, 0); \
        acc[_i][3] = __builtin_amdgcn_mfma_f32_16x16x32_f16(_a, _b3, acc[_i][3], 0, 0, 0); \
        __builtin_amdgcn_s_setprio(0); \
    } \
} while (0)

__global__ __launch_bounds__(512, 4) void k_argmin_mfma(
    const f16* __restrict__ xh, const f16* __restrict__ xl,
    const f16* __restrict__ eh, const f16* __restrict__ el,
    const float* __restrict__ enorm, unsigned long long* __restrict__ rowmin) {
    __shared__ f16 As[2][8192];   // 2 x 16384 B: 256 rows x 32 f16 (superrow layout)
    __shared__ f16 Bs[2][4096];   // 2 x  8192 B: 128 rows x 32 f16
    __shared__ float en_s[128];
    // post-loop overlays on As buf0 (dead after kt=22; final tile reads buf1):
    float* mval = (float*)&As[0][0];                 // [256][2]
    int*   midx = (int*)((char*)&As[0][0] + 2048);   // [256][2]

    const int t = threadIdx.x;
    const int lane = t & 63, wid = t >> 6;
    const int wr = wid >> 1, wc = wid & 1;           // 4 row-groups x 2 col-groups
    const int m = lane & 15, q = lane >> 4;

    // XCD-chunked dispatch: each XCD owns 16 contiguous row-blocks; col outermost.
    // B-panel (128 cols x 768 K = 196KB) L2-resident per XCD; A chunk LLC-resident.
    const int bid = blockIdx.x;
    const int xcd = bid & 7, seq = bid >> 3;
    const int colb = seq >> 4;                 // 0..63
    const int rowb = (xcd << 4) | (seq & 15);  // 0..127
    const int BR = rowb * 256;
    const int CBb = colb * 128;

    char* AsB = (char*)&As[0][0];
    char* BsB = (char*)&Bs[0][0];

    if (t < 128) en_s[t] = enorm[CBb + t];

    // ---- hoisted staging addresses (inverse superrow swizzle on global source) ----
    // gload lane l writes LDS byte 16*l: superrow u=l>>3, chunk c7=l&7.
    // stored chunk c7 holds logical (row 2u+h, elems qsel*8..) with h,qsel from c7^u.
    const int u8 = lane >> 3, cx = (lane & 7) ^ u8;
    const int stg_row = 2 * u8 + (cx >> 2);
    const int stg_col = (cx & 3) * 8;
    const size_t aoff = (size_t)(BR + wid * 32 + stg_row) * DD + stg_col;
    const size_t boff = (size_t)(CBb + wid * 16 + stg_row) * DD + stg_col;
    char* const ldsAw = AsB + wid * 2048;
    char* const ldsBw = BsB + wid * 1024;

    // ---- hoisted read addresses (swizzled ds_read) ----
    // frag row r = group + i*16 + m, elems q*8..: byte = (r>>1)*128 + 16*(((m&1)*4+q)^(m>>1))
    const int rdsw = (((((m & 1) << 2) | q)) ^ (m >> 1)) * 16;
    const int abyte = wr * 4096 + (m >> 1) * 128 + rdsw;
    const int bbyte = wc * 4096 + (m >> 1) * 128 + rdsw;

    f32x4 acc[4][4];
    #pragma unroll
    for (int i = 0; i < 4; ++i)
        #pragma unroll
        for (int j = 0; j < 4; ++j) acc[i][j] = (f32x4){0.f, 0.f, 0.f, 0.f};

    // prologue: stage K-tile 0 into buf0 (syncthreads drains vmcnt)
    STAGE(0, 0);
    __syncthreads();

    #pragma unroll 1
    for (int kp = 0; kp < 11; ++kp) {
        const int kt0 = kp * 2;
        BODY(kt0, 0, 1);
        BODY(kt0 + 1, 1, 0);
    }
    BODY(22, 0, 1);
    FINALT(1);

    // ---- argmin epilogue ----
    #pragma unroll
    for (int i = 0; i < 4; ++i)
    #pragma unroll
    for (int r = 0; r < 4; ++r) {
        float v = 3.4e38f; int ii = 0;
        #pragma unroll
        for (int j = 0; j < 4; ++j) {
            int c = wc * 64 + j * 16 + m;
            float dv = en_s[c] - 2.f * acc[i][j][r];
            if (dv < v) { v = dv; ii = CBb + c; }
        }
        #pragma unroll
        for (int off = 1; off < 16; off <<= 1) {
            float v2 = __shfl_xor(v, off);
            int i2 = __shfl_xor(ii, off);
            if (v2 < v || (v2 == v && i2 < ii)) { v = v2; ii = i2; }
        }
        if (m == 0) {
            int row = wr * 64 + i * 16 + q * 4 + r;
            mval[row * 2 + wc] = v; midx[row * 2 + wc] = ii;
        }
    }
    __syncthreads();
    if (t < 256) {
        float v = mval[t * 2]; int ii = midx[t * 2];
        float v2 = mval[t * 2 + 1]; int i2 = midx[t * 2 + 1];
        if (v2 < v || (v2 == v && i2 < ii)) { v = v2; ii = i2; }
        unsigned int u = __float_as_uint(v);
        u = (u & 0x80000000u) ? ~u : (u | 0x80000000u);
        unsigned long long key = ((unsigned long long)u << 32) | (unsigned int)ii;
        atomicMin(rowmin + BR + t, key);
    }
}

// ---------- decode rowmin -> idx, histogram, loss sum ----------
__global__ void k_finalize(const unsigned long long* __restrict__ rowmin,
                           int* __restrict__ idx, int* __restrict__ cnt,
                           float* __restrict__ lossAcc) {
    __shared__ float red[4];
    int t = threadIdx.x;
    int n = blockIdx.x * 256 + t;
    unsigned long long p = rowmin[n];
    unsigned int u = (unsigned int)(p >> 32);
    unsigned int u2 = (u & 0x80000000u) ? (u ^ 0x80000000u) : ~u;
    float v = __uint_as_float(u2);
    int i = (int)(unsigned int)(p & 0xFFFFFFFFu);
    idx[n] = i;
    atomicAdd(&cnt[i], 1);
    for (int off = 32; off > 0; off >>= 1) v += __shfl_xor(v, off);
    if ((t & 63) == 0) red[t >> 6] = v;
    __syncthreads();
    if (t == 0) atomicAdd(&lossAcc[0], red[0] + red[1] + red[2] + red[3]);
}

// ---------- single-block stats ----------
__global__ void k_stats(const int* __restrict__ cnt, const float* __restrict__ cluster_size,
                        const float* __restrict__ lossAcc,
                        float* __restrict__ out_ncs, float* __restrict__ out_loss,
                        float* __restrict__ out_perp,
                        float* __restrict__ smoothed, int* __restrict__ offsets) {
    __shared__ float rn[256], rp[256];
    __shared__ int rc[256];
    __shared__ int base_s[256];
    int t = threadIdx.x;
    float s_n = 0.f, s_pl = 0.f;
    int s_c = 0;
    float ncs_loc[32];
    #pragma unroll
    for (int i = 0; i < 32; ++i) {
        int k = t * 32 + i;
        int ci = cnt[k];
        float c = (float)ci;
        float ncs = cluster_size[k] * 0.99f + 0.01f * c;
        out_ncs[k] = ncs;
        ncs_loc[i] = ncs;
        s_n += ncs;
        float p = c * (1.0f / 32768.0f);
        s_pl += p * logf(p + 1e-10f);
        s_c += ci;
    }
    rn[t] = s_n; rp[t] = s_pl; rc[t] = s_c;
    for (int off = 128; off > 0; off >>= 1) {
        __syncthreads();
        if (t < off) { rn[t] += rn[t + off]; rp[t] += rp[t + off]; }
    }
    __syncthreads();
    float ntot = rn[0];
    if (t == 0) {
        out_loss[0] = 0.25f * (lossAcc[0] + lossAcc[1]) * (1.0f / 8388608.0f);
        out_perp[0] = expf(-rp[0]);
    }
    #pragma unroll
    for (int i = 0; i < 32; ++i) {
        int k = t * 32 + i;
        float ncs = ncs_loc[i];
        smoothed[k] = ntot * (ncs + 1e-5f) / (ntot + ncs * 1e-5f);
    }
    __syncthreads();
    if (t == 0) {
        int run = 0;
        for (int qq = 0; qq < 256; ++qq) { base_s[qq] = run; run += rc[qq]; }
    }
    __syncthreads();
    int run = base_s[t];
    #pragma unroll
    for (int i = 0; i < 32; ++i) {
        int k = t * 32 + i;
        offsets[k] = run;
        run += cnt[k];
    }
}

// ---------- counting-sort scatter ----------
__global__ void k_scatter(const int* __restrict__ idx, const int* __restrict__ offsets,
                          int* __restrict__ cursor, int* __restrict__ order) {
    int n = blockIdx.x * 256 + threadIdx.x;
    int k = idx[n];
    int pos = offsets[k] + atomicAdd(&cursor[k], 1);
    order[pos] = n;
}

// ---------- dwT[k][d] (f16) = segment_sum of x ----------
__global__ void k_dw(const int* __restrict__ cnt, const int* __restrict__ offsets,
                     const int* __restrict__ order, const f16* __restrict__ xh,
                     const f16* __restrict__ xl, f16* __restrict__ dwT) {
    int k = blockIdx.x;
    int t = threadIdx.x;
    int c = cnt[k], base = offsets[k];
    float s = 0.f;
    for (int i = 0; i < c; ++i) {
        int n = order[base + i];
        s += (float)xh[(size_t)n * DD + t] + (float)xl[(size_t)n * DD + t];
    }
    dwT[(size_t)k * DD + t] = (f16)s;
}

// ---------- new_ema_embed / new_embed ----------
__global__ void k_update_embed(const f16* __restrict__ dwT, const float* __restrict__ ema_embed,
                               const float* __restrict__ smoothed,
                               float* __restrict__ out_embed, float* __restrict__ out_ema) {
    __shared__ float tile[32][260];
    int bx = blockIdx.x, t = threadIdx.x;
    int d0 = (bx & 7) * 32, k0 = (bx >> 3) * 256;
    {
        int kk = t >> 3, dq = (t & 7) * 4;
        for (int i = 0; i < 8; ++i) {
            int kl = kk + i * 32;
            f16x4 v = *(const f16x4*)(dwT + (size_t)(k0 + kl) * DD + d0 + dq);
            tile[dq + 0][kl] = (float)v[0]; tile[dq + 1][kl] = (float)v[1];
            tile[dq + 2][kl] = (float)v[2]; tile[dq + 3][kl] = (float)v[3];
        }
    }
    __syncthreads();
    float sm = smoothed[k0 + t];
    for (int dv = 0; dv < 32; ++dv) {
        size_t o = (size_t)(d0 + dv) * KC + k0 + t;
        float dw = tile[dv][t];
        float ne = ema_embed[o] * 0.99f + 0.01f * dw;
        out_ema[o] = ne;
        out_embed[o] = ne / sm;
    }
}

// ---------- quantize gather + NCHW writeback ----------
__global__ __launch_bounds__(256, 2) void k_quantize_out(
    const int* __restrict__ idx, const f16* __restrict__ eh, const f16* __restrict__ el,
    float* __restrict__ out) {
    __shared__ float qv[256][68];
    __shared__ int li[64];
    int t = threadIdx.x;
    int n0 = blockIdx.x * 64;
    int b = n0 >> 10, h0 = (n0 >> 5) & 31;
    if (t < 64) li[t] = idx[n0 + t];
    __syncthreads();
    {
        int r = t >> 2, dq4 = (t & 3) * 4;
        const f16* srch = eh + (size_t)li[r] * DD;
        const f16* srcl = el + (size_t)li[r] * DD;
        for (int i = 0; i < 16; ++i) {
            int d = dq4 + i * 16;
            f16x4 hv = *(const f16x4*)(srch + d);
            f16x4 lv = *(const f16x4*)(srcl + d);
            qv[d + 0][r] = (float)hv[0] + (float)lv[0];
            qv[d + 1][r] = (float)hv[1] + (float)lv[1];
            qv[d + 2][r] = (float)hv[2] + (float)lv[2];
            qv[d + 3][r] = (float)hv[3] + (float)lv[3];
        }
    }
    __syncthreads();
    {
        int p = t >> 7, tt = t & 127;
        int wq = (tt & 7) * 4, d0 = tt >> 3;
        float* dst = out + (size_t)b * 262144 + (size_t)(h0 + p) * 32 + wq;
        for (int i = 0; i < 16; ++i) {
            int d = d0 + i * 16;
            float4 v = *(const float4*)&qv[d][p * 32 + wq];
            *(float4*)(dst + (size_t)d * 1024) = v;
        }
    }
}

extern "C" void kernel_launch(void* const* d_in, const int* in_sizes, int n_in,
                              void* d_out, int out_size, void* d_ws, size_t ws_size,
                              hipStream_t stream) {
    (void)in_sizes; (void)n_in; (void)out_size; (void)ws_size;
    const float* x            = (const float*)d_in[0];
    const float* embed        = (const float*)d_in[1];
    const float* cluster_size = (const float*)d_in[2];
    const float* ema_embed    = (const float*)d_in[3];
    float* out = (float*)d_out;
    char* ws = (char*)d_ws;

    f16*   xh       = (f16*)  (ws + 0);           // 16,777,216
    f16*   xl       = (f16*)  (ws + 16777216);    // 16,777,216
    f16*   eh       = (f16*)  (ws + 33554432);    //  4,194,304
    f16*   el       = (f16*)  (ws + 37748736);    //  4,194,304
    float* enorm    = (float*)(ws + 41943040);    //     32,768
    float* smoothed = (float*)(ws + 41975808);    //     32,768
    int*   idx      = (int*)  (ws + 42008576);    //    131,072
    int*   cnt      = (int*)  (ws + 42139648);    //     32,768
    int*   cursor   = (int*)  (ws + 42172416);    //     32,768
    int*   offsets  = (int*)  (ws + 42205184);    //     32,768
    float* lossAcc  = (float*)(ws + 42237952);    //        256 (padded)
    unsigned long long* rowmin = (unsigned long long*)(ws + 42238208); // 262,144
    int*   order    = (int*)  (ws + 42238208);    // aliases rowmin (used after finalize)
    f16*   dwT      = (f16*)  (ws + 42500352);    //  4,194,304  -> total 46,694,656

    float* out_q    = out;
    float* out_loss = out + 8388608;
    float* out_perp = out + 8388609;
    float* out_ncs  = out + 8388610;
    float* out_emb  = out + 8396802;
    float* out_ema  = out + 10493954;

    hipMemsetAsync(cnt, 0, 65536, stream);          // cnt + cursor adjacent
    hipMemsetAsync(lossAcc, 0, 8, stream);
    hipMemsetAsync(rowmin, 0xFF, 262144, stream);

    k_convert_x<<<512, 256, 0, stream>>>(x, xh, xl, lossAcc);
    k_convert_e<<<2048, 256, 0, stream>>>(embed, eh, el);
    k_enorm<<<32, 256, 0, stream>>>(embed, enorm);
    k_argmin_mfma<<<8192, 512, 0, stream>>>(xh, xl, eh, el, enorm, rowmin);
    k_finalize<<<128, 256, 0, stream>>>(rowmin, idx, cnt, lossAcc);
    k_stats<<<1, 256, 0, stream>>>(cnt, cluster_size, lossAcc, out_ncs, out_loss, out_perp,
                                   smoothed, offsets);
    k_scatter<<<128, 256, 0, stream>>>(idx, offsets, cursor, order);
    k_dw<<<8192, 256, 0, stream>>>(cnt, offsets, order, xh, xl, dwT);
    k_update_embed<<<256, 256, 0, stream>>>(dwT, ema_embed, smoothed, out_emb, out_ema);
    k_quantize_out<<<512, 256, 0, stream>>>(idx, eh, el, out_q);
}